// Round 23
// baseline (183.296 us; speedup 1.0000x reference)
//
#include <hip/hip_runtime.h>
#include <hip/hip_bf16.h>
#include <stdint.h>

// Problem constants (fixed by the reference)
#define P 2048       // D_STATE
#define HN 64        // D_INPUT
#define L 16384      // kernel_size
#define BN 32        // l-columns per block

typedef __bf16 bf16_t;
typedef bf16_t bf16x8 __attribute__((ext_vector_type(8)));
typedef float f32x16 __attribute__((ext_vector_type(16)));

__device__ __forceinline__ float2 cmul(float2 a, float2 b) {
    return make_float2(a.x * b.x - a.y * b.y, a.x * b.y + a.y * b.x);
}

__device__ __forceinline__ uint32_t packbf(float2 v) {
    union { __hip_bfloat162 v; uint32_t u; } cv;
    cv.v = __float22bfloat162_rn(make_float2(v.x, v.y));
    return cv.u;
}

// ---------------------------------------------------------------------------
// Prep 1 (grid 128 x 256): block-invariant tables.
// (a) wexp: W in bf16 32x32-MFMA A-fragment order; granule gid =
//     kt*256 + q*128 + mt*64 + lane -> A[m=mt*32+(lane&31)], p-run =
//     kt*16 + q*8 + (lane>>5)*4, (W_re, -W_im) bf16 pairs.
// (b) Tcol[p*32 + lc] = A_p^lc, lc in [0,32)  (float2, 512 KB).
__global__ void mv_prep1(const float* __restrict__ Win,
                         const float* __restrict__ Ain,
                         uint4* __restrict__ wexp,
                         float2* __restrict__ tcol) {
    int gid = blockIdx.x * 256 + threadIdx.x;   // 32768
    {   // (a) wexp
        int lane = gid & 63;
        int mt = (gid >> 6) & 1;
        int q = (gid >> 7) & 1;
        int kt = gid >> 8;
        int m = mt * 32 + (lane & 31);
        int p0 = kt * 16 + q * 8 + (lane >> 5) * 4;
        const float4* wp = (const float4*)(Win + (size_t)(m * P + p0) * 2);
        float4 f0 = wp[0], f1 = wp[1];
        float re[4] = {f0.x, f0.z, f1.x, f1.z};
        float im[4] = {f0.y, f0.w, f1.y, f1.w};
        uint32_t o[4];
#pragma unroll
        for (int j = 0; j < 4; ++j)
            o[j] = packbf(make_float2(re[j], -im[j]));
        wexp[gid] = make_uint4(o[0], o[1], o[2], o[3]);
    }
    {   // (b) Tcol
        int p = gid >> 4;
        int e = gid & 15;
        float2 a = *(const float2*)(Ain + 2 * p);
        float2 a2 = cmul(a, a);
        float2 r = make_float2(1.f, 0.f);
        float2 sq = a2;
#pragma unroll
        for (int b = 0; b < 4; ++b) {
            if ((e >> b) & 1) r = cmul(r, sq);
            sq = cmul(sq, sq);
        }
        tcol[(size_t)p * 32 + 2 * e] = r;
        tcol[(size_t)p * 32 + 2 * e + 1] = cmul(r, a);
    }
}

// ---------------------------------------------------------------------------
// Prep 2 (grid 4096 x 256 = 1M threads): TB[bn*P + p] = A_p^(32*bn),
// bn in [0,512). One entry per thread, coalesced writes, ~19 cmuls.
__global__ void mv_prep2(const float* __restrict__ Ain,
                         float2* __restrict__ tb) {
    int gid = blockIdx.x * 256 + threadIdx.x;   // 1048576
    int p = gid & (P - 1);
    int bn = gid >> 11;                          // [0,512)
    float2 a = *(const float2*)(Ain + 2 * p);
    float2 a32 = a;
#pragma unroll
    for (int s = 0; s < 5; ++s) a32 = cmul(a32, a32);   // A^32
    float2 r = make_float2(1.f, 0.f);
    float2 sq = a32;
#pragma unroll
    for (int b = 0; b < 9; ++b) {                        // bn < 512: 9 bits
        if ((bn >> b) & 1) r = cmul(r, sq);
        sq = cmul(sq, sq);
    }
    tb[(size_t)bn * P + p] = r;                          // A^(32*bn)
}

// ---------------------------------------------------------------------------
// Main: grid 512 x 512 thr (8 waves). Wave w: kt in [16w, 16w+16) (split-K
// 8 ways), both 32-row m-tiles, 32x32x16 MFMA, B generated in-register
// (Base x Tcol). No barriers in the K-loop. Two-stage LDS reduction.
__global__ void __launch_bounds__(512, 6) mv_main(
    const uint4* __restrict__ wexp,
    const float2* __restrict__ Tcol,
    const float2* __restrict__ TB,
    float* __restrict__ out) {
    __shared__ __align__(16) float2 Base[P];   // 16 KB: A_p^(32*bn)
    __shared__ float Red[4][2048];             // 32 KB: staged partials

    const int t = threadIdx.x;      // 0..511
    const int bn = blockIdx.x;
    const int w = t >> 6;           // wave 0..7
    const int lw = t & 63;

    {   // Base <- TB[bn] (16 KB coalesced)
        const float4* src = (const float4*)(TB + (size_t)bn * P);
        float4* dst = (float4*)Base;
        dst[t] = src[t];
        dst[512 + t] = src[512 + t];
    }
    __syncthreads();

    const int n = lw & 31;
    const int kh = lw >> 5;

    f32x16 acc0, acc1;
#pragma unroll
    for (int r = 0; r < 16; ++r) { acc0[r] = 0.f; acc1[r] = 0.f; }

    const int kt0 = w * 16;
    const uint4* wq = wexp + (size_t)kt0 * 256 + lw;
    const float2* tq = Tcol + (size_t)kt0 * 512 + kh * 128 + n;
    const float4* bb = ((const float4*)Base) + kt0 * 8 + kh * 2;

#pragma unroll 2
    for (int kt = 0; kt < 16; ++kt) {
        // all independent loads up front (compiler batches vmcnt)
        uint4 a00 = wq[0];     // mt0 q0
        uint4 a10 = wq[64];    // mt1 q0
        uint4 a01 = wq[128];   // mt0 q1
        uint4 a11 = wq[192];   // mt1 q1
        float2 t0 = tq[0],   t1 = tq[32],  t2 = tq[64],  t3 = tq[96];
        float2 t4 = tq[256], t5 = tq[288], t6 = tq[320], t7 = tq[352];
        float4 b0 = bb[0], b1 = bb[1], b2 = bb[4], b3 = bb[5];
        {   // q = 0
            uint32_t f0 = packbf(cmul(make_float2(b0.x, b0.y), t0));
            uint32_t f1 = packbf(cmul(make_float2(b0.z, b0.w), t1));
            uint32_t f2 = packbf(cmul(make_float2(b1.x, b1.y), t2));
            uint32_t f3 = packbf(cmul(make_float2(b1.z, b1.w), t3));
            union { uint4 u; bf16x8 b; } bf, am0, am1;
            bf.u = make_uint4(f0, f1, f2, f3);
            am0.u = a00; am1.u = a10;
            acc0 = __builtin_amdgcn_mfma_f32_32x32x16_bf16(am0.b, bf.b, acc0, 0, 0, 0);
            acc1 = __builtin_amdgcn_mfma_f32_32x32x16_bf16(am1.b, bf.b, acc1, 0, 0, 0);
        }
        {   // q = 1
            uint32_t f0 = packbf(cmul(make_float2(b2.x, b2.y), t4));
            uint32_t f1 = packbf(cmul(make_float2(b2.z, b2.w), t5));
            uint32_t f2 = packbf(cmul(make_float2(b3.x, b3.y), t6));
            uint32_t f3 = packbf(cmul(make_float2(b3.z, b3.w), t7));
            union { uint4 u; bf16x8 b; } bf, am0, am1;
            bf.u = make_uint4(f0, f1, f2, f3);
            am0.u = a01; am1.u = a11;
            acc0 = __builtin_amdgcn_mfma_f32_32x32x16_bf16(am0.b, bf.b, acc0, 0, 0, 0);
            acc1 = __builtin_amdgcn_mfma_f32_32x32x16_bf16(am1.b, bf.b, acc1, 0, 0, 0);
        }
        wq += 256; tq += 512; bb += 8;
    }

    // ---- staged cross-wave reduction (split-K over 8 waves) ----
    if (w < 4) {
#pragma unroll
        for (int r = 0; r < 16; ++r) {
            Red[w][r * 64 + lw] = acc0[r];
            Red[w][(16 + r) * 64 + lw] = acc1[r];
        }
    }
    __syncthreads();
    if (w >= 4) {
#pragma unroll
        for (int r = 0; r < 16; ++r) {
            Red[w - 4][r * 64 + lw] += acc0[r];
            Red[w - 4][(16 + r) * 64 + lw] += acc1[r];
        }
    }
    __syncthreads();

    // C/D layout (m74): col = lane&31, row = (r&3) + 8*(r>>2) + 4*(lane>>5)
#pragma unroll
    for (int i = 0; i < 4; ++i) {
        int idx = i * 512 + t;
        float s = Red[0][idx] + Red[1][idx] + Red[2][idx] + Red[3][idx];
        int lane = idx & 63;
        int r = (idx >> 6) & 15;
        int mt = idx >> 10;
        int row = (r & 3) + 8 * (r >> 2) + 4 * (lane >> 5);
        int hh = mt * 32 + row;
        int ll = bn * BN + (lane & 31);
        out[(size_t)hh * L + ll] = s;
    }
}

// ---------------------------------------------------------------------------
extern "C" void kernel_launch(void* const* d_in, const int* in_sizes, int n_in,
                              void* d_out, int out_size, void* d_ws, size_t ws_size,
                              hipStream_t stream) {
    const float* Ain = nullptr;
    const float* Win = nullptr;
    for (int i = 0; i < n_in; ++i) {
        if (in_sizes[i] == 2 * P) Ain = (const float*)d_in[i];
        else if (in_sizes[i] == 2 * HN * P) Win = (const float*)d_in[i];
    }
    if (!Ain) Ain = (const float*)d_in[0];
    if (!Win) Win = (const float*)d_in[1];
    (void)out_size; (void)ws_size;                          // ws = 256 MB (measured R20)
    uint4* wexp = (uint4*)d_ws;                             // 512 KB
    float2* tcol = (float2*)((char*)d_ws + 512 * 1024);     // +512 KB
    float2* tb = (float2*)((char*)d_ws + 1024 * 1024);      // +8 MB
    mv_prep1<<<128, 256, 0, stream>>>(Win, Ain, wexp, tcol);
    mv_prep2<<<4096, 256, 0, stream>>>(Ain, tb);
    mv_main<<<L / BN, 512, 0, stream>>>(wexp, tcol, tb, (float*)d_out);
}

// Round 24
// 91.219 us; speedup vs baseline: 2.0094x; 2.0094x over previous
//
#include <hip/hip_runtime.h>
#include <hip/hip_bf16.h>
#include <stdint.h>

// Problem constants (fixed by the reference)
#define P 2048       // D_STATE
#define HN 64        // D_INPUT
#define L 16384      // kernel_size
#define BN 32        // l-columns per block

typedef __bf16 bf16_t;
typedef bf16_t bf16x8 __attribute__((ext_vector_type(8)));
typedef float f32x16 __attribute__((ext_vector_type(16)));

__device__ __forceinline__ float2 cmul(float2 a, float2 b) {
    return make_float2(a.x * b.x - a.y * b.y, a.x * b.y + a.y * b.x);
}

__device__ __forceinline__ uint32_t packbf(float2 v) {
    union { __hip_bfloat162 v; uint32_t u; } cv;
    cv.v = __float22bfloat162_rn(make_float2(v.x, v.y));
    return cv.u;
}

// ---------------------------------------------------------------------------
// Prep 1 (grid 128 x 256): block-invariant tables.
// (a) wexp: W in bf16 32x32-MFMA A-fragment order; granule gid =
//     kt*256 + q*128 + mt*64 + lane -> A[m=mt*32+(lane&31)], p-run =
//     kt*16 + q*8 + (lane>>5)*4, (W_re, -W_im) bf16 pairs.
// (b) Tcol[p*32 + lc] = A_p^lc, lc in [0,32)  (float2, 512 KB).
__global__ void mv_prep1(const float* __restrict__ Win,
                         const float* __restrict__ Ain,
                         uint4* __restrict__ wexp,
                         float2* __restrict__ tcol) {
    int gid = blockIdx.x * 256 + threadIdx.x;   // 32768
    {   // (a) wexp
        int lane = gid & 63;
        int mt = (gid >> 6) & 1;
        int q = (gid >> 7) & 1;
        int kt = gid >> 8;
        int m = mt * 32 + (lane & 31);
        int p0 = kt * 16 + q * 8 + (lane >> 5) * 4;
        const float4* wp = (const float4*)(Win + (size_t)(m * P + p0) * 2);
        float4 f0 = wp[0], f1 = wp[1];
        float re[4] = {f0.x, f0.z, f1.x, f1.z};
        float im[4] = {f0.y, f0.w, f1.y, f1.w};
        uint32_t o[4];
#pragma unroll
        for (int j = 0; j < 4; ++j)
            o[j] = packbf(make_float2(re[j], -im[j]));
        wexp[gid] = make_uint4(o[0], o[1], o[2], o[3]);
    }
    {   // (b) Tcol
        int p = gid >> 4;
        int e = gid & 15;
        float2 a = *(const float2*)(Ain + 2 * p);
        float2 a2 = cmul(a, a);
        float2 r = make_float2(1.f, 0.f);
        float2 sq = a2;
#pragma unroll
        for (int b = 0; b < 4; ++b) {
            if ((e >> b) & 1) r = cmul(r, sq);
            sq = cmul(sq, sq);
        }
        tcol[(size_t)p * 32 + 2 * e] = r;
        tcol[(size_t)p * 32 + 2 * e + 1] = cmul(r, a);
    }
}

// ---------------------------------------------------------------------------
// Prep 2 (grid 4096 x 256 = 1M threads): TB[bn*P + p] = A_p^(32*bn),
// bn in [0,512). One entry per thread, coalesced writes, ~19 cmuls.
__global__ void mv_prep2(const float* __restrict__ Ain,
                         float2* __restrict__ tb) {
    int gid = blockIdx.x * 256 + threadIdx.x;   // 1048576
    int p = gid & (P - 1);
    int bn = gid >> 11;                          // [0,512)
    float2 a = *(const float2*)(Ain + 2 * p);
    float2 a32 = a;
#pragma unroll
    for (int s = 0; s < 5; ++s) a32 = cmul(a32, a32);   // A^32
    float2 r = make_float2(1.f, 0.f);
    float2 sq = a32;
#pragma unroll
    for (int b = 0; b < 9; ++b) {                        // bn < 512: 9 bits
        if ((bn >> b) & 1) r = cmul(r, sq);
        sq = cmul(sq, sq);
    }
    tb[(size_t)bn * P + p] = r;                          // A^(32*bn)
}

// ---------------------------------------------------------------------------
// Main: grid 512 x 512 thr (8 waves). Wave w: kt in [16w, 16w+16) (split-K
// 8 ways), both 32-row m-tiles, 32x32x16 MFMA, B generated in-register
// (Base x Tcol). No barriers in the K-loop. Two-stage LDS reduction.
// __launch_bounds__(512, 4): 4 waves/SIMD -> VGPR cap 128 (m69); R23's
// (512,6) capped VGPR at 40 -> catastrophic spill (WRITE_SIZE 79 MB).
__global__ void __launch_bounds__(512, 4) mv_main(
    const uint4* __restrict__ wexp,
    const float2* __restrict__ Tcol,
    const float2* __restrict__ TB,
    float* __restrict__ out) {
    __shared__ __align__(16) float2 Base[P];   // 16 KB: A_p^(32*bn)
    __shared__ float Red[4][2048];             // 32 KB: staged partials

    const int t = threadIdx.x;      // 0..511
    const int bn = blockIdx.x;
    const int w = t >> 6;           // wave 0..7
    const int lw = t & 63;

    {   // Base <- TB[bn] (16 KB coalesced)
        const float4* src = (const float4*)(TB + (size_t)bn * P);
        float4* dst = (float4*)Base;
        dst[t] = src[t];
        dst[512 + t] = src[512 + t];
    }
    __syncthreads();

    const int n = lw & 31;
    const int kh = lw >> 5;

    f32x16 acc0, acc1;
#pragma unroll
    for (int r = 0; r < 16; ++r) { acc0[r] = 0.f; acc1[r] = 0.f; }

    const int kt0 = w * 16;
    const uint4* wq = wexp + (size_t)kt0 * 256 + lw;
    const float2* tq = Tcol + (size_t)kt0 * 512 + kh * 128 + n;
    const float4* bb = ((const float4*)Base) + kt0 * 8 + kh * 2;

#pragma unroll 2
    for (int kt = 0; kt < 16; ++kt) {
        // all independent loads up front (compiler batches vmcnt)
        uint4 a00 = wq[0];     // mt0 q0
        uint4 a10 = wq[64];    // mt1 q0
        uint4 a01 = wq[128];   // mt0 q1
        uint4 a11 = wq[192];   // mt1 q1
        float2 t0 = tq[0],   t1 = tq[32],  t2 = tq[64],  t3 = tq[96];
        float2 t4 = tq[256], t5 = tq[288], t6 = tq[320], t7 = tq[352];
        float4 b0 = bb[0], b1 = bb[1], b2 = bb[4], b3 = bb[5];
        {   // q = 0
            uint32_t f0 = packbf(cmul(make_float2(b0.x, b0.y), t0));
            uint32_t f1 = packbf(cmul(make_float2(b0.z, b0.w), t1));
            uint32_t f2 = packbf(cmul(make_float2(b1.x, b1.y), t2));
            uint32_t f3 = packbf(cmul(make_float2(b1.z, b1.w), t3));
            union { uint4 u; bf16x8 b; } bf, am0, am1;
            bf.u = make_uint4(f0, f1, f2, f3);
            am0.u = a00; am1.u = a10;
            acc0 = __builtin_amdgcn_mfma_f32_32x32x16_bf16(am0.b, bf.b, acc0, 0, 0, 0);
            acc1 = __builtin_amdgcn_mfma_f32_32x32x16_bf16(am1.b, bf.b, acc1, 0, 0, 0);
        }
        {   // q = 1
            uint32_t f0 = packbf(cmul(make_float2(b2.x, b2.y), t4));
            uint32_t f1 = packbf(cmul(make_float2(b2.z, b2.w), t5));
            uint32_t f2 = packbf(cmul(make_float2(b3.x, b3.y), t6));
            uint32_t f3 = packbf(cmul(make_float2(b3.z, b3.w), t7));
            union { uint4 u; bf16x8 b; } bf, am0, am1;
            bf.u = make_uint4(f0, f1, f2, f3);
            am0.u = a01; am1.u = a11;
            acc0 = __builtin_amdgcn_mfma_f32_32x32x16_bf16(am0.b, bf.b, acc0, 0, 0, 0);
            acc1 = __builtin_amdgcn_mfma_f32_32x32x16_bf16(am1.b, bf.b, acc1, 0, 0, 0);
        }
        wq += 256; tq += 512; bb += 8;
    }

    // ---- staged cross-wave reduction (split-K over 8 waves) ----
    if (w < 4) {
#pragma unroll
        for (int r = 0; r < 16; ++r) {
            Red[w][r * 64 + lw] = acc0[r];
            Red[w][(16 + r) * 64 + lw] = acc1[r];
        }
    }
    __syncthreads();
    if (w >= 4) {
#pragma unroll
        for (int r = 0; r < 16; ++r) {
            Red[w - 4][r * 64 + lw] += acc0[r];
            Red[w - 4][(16 + r) * 64 + lw] += acc1[r];
        }
    }
    __syncthreads();

    // C/D layout (m74): col = lane&31, row = (r&3) + 8*(r>>2) + 4*(lane>>5)
#pragma unroll
    for (int i = 0; i < 4; ++i) {
        int idx = i * 512 + t;
        float s = Red[0][idx] + Red[1][idx] + Red[2][idx] + Red[3][idx];
        int lane = idx & 63;
        int r = (idx >> 6) & 15;
        int mt = idx >> 10;
        int row = (r & 3) + 8 * (r >> 2) + 4 * (lane >> 5);
        int hh = mt * 32 + row;
        int ll = bn * BN + (lane & 31);
        out[(size_t)hh * L + ll] = s;
    }
}

// ---------------------------------------------------------------------------
extern "C" void kernel_launch(void* const* d_in, const int* in_sizes, int n_in,
                              void* d_out, int out_size, void* d_ws, size_t ws_size,
                              hipStream_t stream) {
    const float* Ain = nullptr;
    const float* Win = nullptr;
    for (int i = 0; i < n_in; ++i) {
        if (in_sizes[i] == 2 * P) Ain = (const float*)d_in[i];
        else if (in_sizes[i] == 2 * HN * P) Win = (const float*)d_in[i];
    }
    if (!Ain) Ain = (const float*)d_in[0];
    if (!Win) Win = (const float*)d_in[1];
    (void)out_size; (void)ws_size;                          // ws = 256 MB (measured R20)
    uint4* wexp = (uint4*)d_ws;                             // 512 KB
    float2* tcol = (float2*)((char*)d_ws + 512 * 1024);     // +512 KB
    float2* tb = (float2*)((char*)d_ws + 1024 * 1024);      // +8 MB
    mv_prep1<<<128, 256, 0, stream>>>(Win, Ain, wexp, tcol);
    mv_prep2<<<4096, 256, 0, stream>>>(Ain, tb);
    mv_main<<<L / BN, 512, 0, stream>>>(wexp, tcol, tb, (float*)d_out);
}